// Round 8
// baseline (192.163 us; speedup 1.0000x reference)
//
#include <hip/hip_runtime.h>
#include <hip/hip_bf16.h>
#include <math.h>

// GPT-OSS MoE: rmsnorm -> gate top4 -> mxfp4 MLP1 (MFMA) -> swiglu -> mxfp4 MLP2 (MFMA) -> combine
// E=32, H=1024, I=1024, N=1024 tokens, top-4.

#define NE 32
#define HD 1024
#define ID 1024
#define NTOK 1024
#define R1 2048

typedef __attribute__((ext_vector_type(8)))  short bf16x8;
typedef __attribute__((ext_vector_type(16))) float f32x16;

// ---- workspace layout (bytes) ----
#define TB_OFF   0            // t_bf16 [1024][1024] bf16 = 2 MB
#define A_OFF    2097152      // a      [4096][1024] bf16 = 8 MB
#define YB_OFF   10485760     // yb     [4096][1024] bf16 = 8 MB
#define CNT_OFF  18874368     // counts int[32]
#define OFFS_OFF 18874624     // offsets int[33]
#define TOKL_OFF 18874880     // tok_list int[32*1024]
#define TIDX_OFF 19005952     // top_idx int[1024*4]
#define TWT_OFF  19022336     // top_wt  f32[1024*4]
#define POS_OFF  19038720     // pos_of  int[1024*4]

__device__ __forceinline__ unsigned f2bf(float f) {
    unsigned u = __float_as_uint(f);
    return (u + 0x7FFFu + ((u >> 16) & 1u)) >> 16;   // RNE
}
__device__ __forceinline__ float bf2f(unsigned u) {
    return __uint_as_float(u << 16);
}

// decode 8 fp4 elems (4 boxed int32s = 4 payload bytes = 8 nibbles) -> bf16x8,
// scale folded in as packed exponent add. fp4 zero -> ~2^-96 after scale (negligible).
__device__ __forceinline__ bf16x8 dec8(int4 wv, unsigned dd) {
    unsigned u = __builtin_amdgcn_perm((unsigned)wv.y, (unsigned)wv.x, 0x00000400u);
    unsigned v = __builtin_amdgcn_perm((unsigned)wv.w, (unsigned)wv.z, 0x04000000u);
    unsigned packed = __builtin_amdgcn_perm(v, u, 0x07060100u);   // {b0,b1,b2,b3}
    unsigned selE = packed & 0x07070707u;
    unsigned sE   = packed & 0x08080808u;
    unsigned ph   = packed >> 4;
    unsigned selO = ph & 0x07070707u;
    unsigned sO   = ph & 0x08080808u;
    const unsigned PH_hi = 0x40404040u, PH_lo = 0x3F3F3F14u;
    const unsigned PL_hi = 0xC0804000u, PL_lo = 0xC0800000u;
    unsigned hbE = __builtin_amdgcn_perm(PH_hi, PH_lo, selE) | (sE << 4);
    unsigned lbE = __builtin_amdgcn_perm(PL_hi, PL_lo, selE);
    unsigned hbO = __builtin_amdgcn_perm(PH_hi, PH_lo, selO) | (sO << 4);
    unsigned lbO = __builtin_amdgcn_perm(PL_hi, PL_lo, selO);
    unsigned mE0 = __builtin_amdgcn_perm(hbE, lbE, 0x05010400u);
    unsigned mE1 = __builtin_amdgcn_perm(hbE, lbE, 0x07030602u);
    unsigned mO0 = __builtin_amdgcn_perm(hbO, lbO, 0x05010400u);
    unsigned mO1 = __builtin_amdgcn_perm(hbO, lbO, 0x07030602u);
    unsigned r0 = __builtin_amdgcn_perm(mO0, mE0, 0x05040100u);
    unsigned r1 = __builtin_amdgcn_perm(mO0, mE0, 0x07060302u);
    unsigned r2 = __builtin_amdgcn_perm(mO1, mE1, 0x05040100u);
    unsigned r3 = __builtin_amdgcn_perm(mO1, mE1, 0x07060302u);
    unsigned o0, o1, o2, o3;
    asm("v_pk_add_u16 %0, %1, %2" : "=v"(o0) : "v"(r0), "v"(dd));
    asm("v_pk_add_u16 %0, %1, %2" : "=v"(o1) : "v"(r1), "v"(dd));
    asm("v_pk_add_u16 %0, %1, %2" : "=v"(o2) : "v"(r2), "v"(dd));
    asm("v_pk_add_u16 %0, %1, %2" : "=v"(o3) : "v"(r3), "v"(dd));
    uint4 o; o.x = o0; o.y = o1; o.z = o2; o.w = o3;
    union { uint4 u4; bf16x8 b; } cv; cv.u4 = o;
    return cv.b;
}

__device__ __forceinline__ void gll16(const void* g, void* l) {
    __builtin_amdgcn_global_load_lds(
        (const __attribute__((address_space(1))) unsigned int*)g,
        (__attribute__((address_space(3))) unsigned int*)l, 16, 0, 0);
}

#define SB __builtin_amdgcn_sched_barrier(0)

// all ds_reads of this wave retired; sync block
#define BAR_READDONE { asm volatile("s_waitcnt lgkmcnt(0)" ::: "memory"); SB; \
                       __builtin_amdgcn_s_barrier(); SB; }

__global__ __launch_bounds__(256) void k_gate(
    const float* __restrict__ x, const float* __restrict__ norm_w,
    const float* __restrict__ gate_w, const float* __restrict__ gate_b,
    ushort* __restrict__ t_bf16, int* __restrict__ top_idx, float* __restrict__ top_wt,
    int* __restrict__ counts, int* __restrict__ tok_list, int* __restrict__ pos_of)
{
    int n = blockIdx.x;
    int tid = threadIdx.x;
    __shared__ float tl[HD];
    __shared__ float red[4];
    __shared__ float logits[NE];

    const float4* xv = (const float4*)(x + (size_t)n * HD);
    float4 v = xv[tid];
    float ss = v.x * v.x + v.y * v.y + v.z * v.z + v.w * v.w;
    #pragma unroll
    for (int off = 32; off; off >>= 1) ss += __shfl_down(ss, off);
    if ((tid & 63) == 0) red[tid >> 6] = ss;
    __syncthreads();
    float tot = red[0] + red[1] + red[2] + red[3];
    float rms = rsqrtf(tot * (1.0f / HD) + 1e-5f);

    float4 w = ((const float4*)norm_w)[tid];
    float4 tv;
    tv.x = v.x * rms * w.x; tv.y = v.y * rms * w.y;
    tv.z = v.z * rms * w.z; tv.w = v.w * rms * w.w;
    ushort4 tb;
    tb.x = (ushort)f2bf(tv.x); tb.y = (ushort)f2bf(tv.y);
    tb.z = (ushort)f2bf(tv.z); tb.w = (ushort)f2bf(tv.w);
    ((ushort4*)(t_bf16 + (size_t)n * HD))[tid] = tb;
    ((float4*)tl)[tid] = tv;
    __syncthreads();

    int wv = tid >> 6, lane = tid & 63;
    for (int j = 0; j < 8; j++) {
        int e = wv * 8 + j;
        const float* gw = gate_w + (size_t)e * HD;
        float p = 0.f;
        #pragma unroll
        for (int q = 0; q < 16; q++) { int kk = lane + q * 64; p += tl[kk] * gw[kk]; }
        #pragma unroll
        for (int off = 32; off; off >>= 1) p += __shfl_down(p, off);
        if (lane == 0) logits[e] = p + gate_b[e];
    }
    __syncthreads();

    if (tid == 0) {
        float vals[4]; int idx[4];
        unsigned used = 0;
        #pragma unroll
        for (int kk = 0; kk < 4; kk++) {
            float best = -1e30f; int bi = 0;
            for (int e2 = 0; e2 < NE; e2++) {
                if (used & (1u << e2)) continue;
                if (logits[e2] > best) { best = logits[e2]; bi = e2; }
            }
            used |= 1u << bi; vals[kk] = best; idx[kk] = bi;
        }
        float m = vals[0], s = 0.f, ex[4];
        #pragma unroll
        for (int kk = 0; kk < 4; kk++) { ex[kk] = __expf(vals[kk] - m); s += ex[kk]; }
        float inv = 1.0f / s;
        #pragma unroll
        for (int kk = 0; kk < 4; kk++) {
            top_idx[n * 4 + kk] = idx[kk];
            top_wt[n * 4 + kk] = ex[kk] * inv;
            int slot = atomicAdd(counts + idx[kk], 1);
            tok_list[idx[kk] * NTOK + slot] = n;
            pos_of[n * 4 + kk] = slot;
        }
    }
}

__global__ void k_prefix(const int* __restrict__ counts, int* __restrict__ offsets)
{
    if (threadIdx.x == 0) {
        int s = 0;
        for (int e = 0; e < NE; e++) { offsets[e] = s; s += counts[e]; }
        offsets[NE] = s;
    }
}

// ---- shared pipeline macros for the MLP kernels ----
// per-tile batch = 10 vmem ops/wave: 4 weight gll + 4 token gll + 2 scale loads.
#define MLP_ISSUE(buf, kt, S0, S1)                                           \
    {                                                                        \
        _Pragma("unroll")                                                    \
        for (int j_ = 0; j_ < 4; j_++)                                       \
            gll16(pw[j_] + (kt) * 128, &wlds[buf][((j_ << 2) + wu) << 10]);  \
        _Pragma("unroll")                                                    \
        for (int i_ = 0; i_ < 4; i_++)                                       \
            gll16(tpp[i_] + (kt) * 64, &tlds[buf][((wu << 2) + i_) << 10]);  \
        S0 = *(const int2*)(spA + (kt) * 2);                                 \
        S1 = *(const int2*)(spB + (kt) * 2);                                 \
    }

#define MLP_COMPUTE(buf, S0, S1)                                             \
    _Pragma("unroll")                                                        \
    for (int ks = 0; ks < 4; ks++) {                                         \
        int s0_ = ks < 2 ? S0.x : S0.y;                                      \
        int s1_ = ks < 2 ? S1.x : S1.y;                                      \
        unsigned d0_ = (unsigned)((s0_ - 127) << 7) & 0xFFFFu;               \
        unsigned d1_ = (unsigned)((s1_ - 127) << 7) & 0xFFFFu;               \
        d0_ |= d0_ << 16; d1_ |= d1_ << 16;                                  \
        int wb_ = (ks * 32 + kh * 16) ^ swzr;                                \
        bf16x8 wf0 = dec8(*(const int4*)&wlds[buf][(wr * 64 + lr) * 128 + wb_], d0_);      \
        bf16x8 wf1 = dec8(*(const int4*)&wlds[buf][(wr * 64 + 32 + lr) * 128 + wb_], d1_); \
        _Pragma("unroll")                                                    \
        for (int mt = 0; mt < 2; mt++) {                                     \
            if (act[mt]) {                                                   \
                bf16x8 af = *(const bf16x8*)&tlds[buf][ks * 4096 +           \
                               (wt * 2 + mt) * 1024 + kh * 512 + lr * 16];   \
                acc[0][mt] = __builtin_amdgcn_mfma_f32_32x32x16_bf16(af, wf0, acc[0][mt], 0, 0, 0); \
                acc[1][mt] = __builtin_amdgcn_mfma_f32_32x32x16_bf16(af, wf1, acc[1][mt], 0, 0, 0); \
            }                                                                \
        }                                                                    \
    }

// steady-state K-loop: counted vmcnt(10), never drained while tiles remain.
#define MLP_KLOOP                                                            \
    MLP_ISSUE(0, 0, scA0, scA1);                                             \
    MLP_ISSUE(1, 1, scB0, scB1);                                             \
    SB;                                                                      \
    asm volatile("s_waitcnt vmcnt(10)" ::: "memory"); SB;                    \
    __builtin_amdgcn_s_barrier(); SB;                                        \
    _Pragma("unroll 1")                                                      \
    for (int kt2 = 0; kt2 < 16; kt2 += 2) {                                  \
        MLP_COMPUTE(0, scA0, scA1);                                          \
        BAR_READDONE;                                                        \
        if (kt2 < 14) {                                                      \
            MLP_ISSUE(0, kt2 + 2, scA0, scA1); SB;                           \
            asm volatile("s_waitcnt vmcnt(10)" ::: "memory");                \
        } else {                                                             \
            asm volatile("s_waitcnt vmcnt(0)" ::: "memory");                 \
        }                                                                    \
        SB; __builtin_amdgcn_s_barrier(); SB;                                \
        MLP_COMPUTE(1, scB0, scB1);                                          \
        BAR_READDONE;                                                        \
        if (kt2 < 14) {                                                      \
            MLP_ISSUE(1, kt2 + 3, scB0, scB1); SB;                           \
            asm volatile("s_waitcnt vmcnt(10)" ::: "memory");                \
            SB; __builtin_amdgcn_s_barrier(); SB;                            \
        }                                                                    \
    }

// MLP1 (MFMA) + swiglu. Block: expert x 128 rows x 128-token chunk.
// Waves 2x2: wave owns 64 rows x 64 tokens. All staging via global_load_lds.
__global__ __launch_bounds__(256, 2) void k_mlp1(
    const ushort* __restrict__ t_bf16, const int* __restrict__ blocks,
    const int* __restrict__ scales, const float* __restrict__ bias,
    const int* __restrict__ counts, const int* __restrict__ offsets,
    const int* __restrict__ tok_list, ushort* __restrict__ a)
{
    int e = blockIdx.y;
    int cnt = counts[e];
    if (cnt == 0) return;
    int r0 = blockIdx.x * 128;
    int tid = threadIdx.x;
    int l = tid & 63;
    int lr = l & 31, kh = l >> 5;
    int wu = __builtin_amdgcn_readfirstlane(tid >> 6);
    int wr = wu >> 1, wt = wu & 1;
    int base = offsets[e];

    __shared__ char tlds[2][16384];   // token tile, k-slot-major [ks4][g4][kh2][32 tok][16B]
    __shared__ char wlds[2][16384];   // boxed weights [128 rows][128B], XOR-swizzled

    int rowA = r0 + wr * 64 + lr;     // wave's row half: wr in {0,1} -> rows 0..63 / 64..127
    int rowB = rowA + 32;
    const int* spA = scales + (size_t)(e * R1 + rowA) * 32;
    const int* spB = scales + (size_t)(e * R1 + rowB) * 32;
    float blA = bias[e * R1 + rowA];
    float blB = bias[e * R1 + rowB];
    asm volatile("" :: "v"(blA), "v"(blB));   // retire bias loads now (vmcnt hygiene)

    int swzr = (lr & 7) << 4;
    int scol = ((l & 7) * 16) ^ (((l >> 3) & 7) << 4);
    const char* pw[4];
    #pragma unroll
    for (int j = 0; j < 4; j++)
        pw[j] = (const char*)blocks +
                (size_t)(e * R1 + r0 + j * 32 + wu * 8 + (l >> 3)) * 2048 + scol;
    int sloc8 = (wu * 2 + kh) * 8;    // staging k-subslot (ushort offset)

    for (int c0 = 0; c0 < cnt; c0 += 128) {
        int nt = min(128, cnt - c0);
        bool act[2] = { (wt * 2) * 32 < nt, (wt * 2 + 1) * 32 < nt };
        const ushort* tpp[4];
        #pragma unroll
        for (int i = 0; i < 4; i++) {
            int t = i * 32 + (l & 31);
            int tc = t < nt ? t : nt - 1;
            tpp[i] = t_bf16 + (size_t)tok_list[e * NTOK + c0 + tc] * HD + sloc8;
        }
        asm volatile("s_waitcnt vmcnt(0)" ::: "memory"); SB;  // flush stores + ptr loads

        int2 scA0, scA1, scB0, scB1;
        f32x16 acc[2][2] = {};

        MLP_KLOOP;

        // epilogue: bias + swiglu (glu/lin = adjacent lanes = adjacent rows)
        #pragma unroll
        for (int nn = 0; nn < 2; nn++) {
            float bl = nn ? blB : blA;
            int row = nn ? rowB : rowA;
            int pcol = row >> 1;
            #pragma unroll
            for (int mt = 0; mt < 2; mt++) {
                if (act[mt]) {
                    #pragma unroll
                    for (int r = 0; r < 16; r++) {
                        float hv = acc[nn][mt][r] + bl;
                        float other = __shfl_xor(hv, 1, 64);
                        int m = (r & 3) + 8 * (r >> 2) + 4 * kh;
                        int tokg = c0 + (wt * 2 + mt) * 32 + m;
                        if (!(l & 1) && tokg < cnt) {
                            float hg = fminf(hv, 7.0f);
                            float hx = fminf(fmaxf(other, -7.0f), 7.0f);
                            float sig = 1.0f / (1.0f + __expf(-1.702f * hg));
                            float av = hg * sig * (hx + 1.0f);
                            a[(size_t)(base + tokg) * ID + pcol] = (ushort)f2bf(av);
                        }
                    }
                }
            }
        }
    }
}

// MLP2 (MFMA). Same pipeline; token source = a (contiguous slots); writes yb.
__global__ __launch_bounds__(256, 2) void k_mlp2(
    const ushort* __restrict__ a, const int* __restrict__ blocks,
    const int* __restrict__ scales, const float* __restrict__ bias,
    const int* __restrict__ counts, const int* __restrict__ offsets,
    ushort* __restrict__ yb)
{
    int e = blockIdx.y;
    int cnt = counts[e];
    if (cnt == 0) return;
    int r0 = blockIdx.x * 128;
    int tid = threadIdx.x;
    int l = tid & 63;
    int lr = l & 31, kh = l >> 5;
    int wu = __builtin_amdgcn_readfirstlane(tid >> 6);
    int wr = wu >> 1, wt = wu & 1;
    int base = offsets[e];

    __shared__ char tlds[2][16384];
    __shared__ char wlds[2][16384];

    int rowA = r0 + wr * 64 + lr;
    int rowB = rowA + 32;
    const int* spA = scales + (size_t)(e * HD + rowA) * 32;
    const int* spB = scales + (size_t)(e * HD + rowB) * 32;
    float blA = bias[e * HD + rowA];
    float blB = bias[e * HD + rowB];
    asm volatile("" :: "v"(blA), "v"(blB));

    int swzr = (lr & 7) << 4;
    int scol = ((l & 7) * 16) ^ (((l >> 3) & 7) << 4);
    const char* pw[4];
    #pragma unroll
    for (int j = 0; j < 4; j++)
        pw[j] = (const char*)blocks +
                (size_t)(e * HD + r0 + j * 32 + wu * 8 + (l >> 3)) * 2048 + scol;
    int sloc8 = (wu * 2 + kh) * 8;

    for (int c0 = 0; c0 < cnt; c0 += 128) {
        int nt = min(128, cnt - c0);
        bool act[2] = { (wt * 2) * 32 < nt, (wt * 2 + 1) * 32 < nt };
        const ushort* tpp[4];
        #pragma unroll
        for (int i = 0; i < 4; i++) {
            int t = i * 32 + (l & 31);
            int tc = t < nt ? t : nt - 1;
            tpp[i] = a + (size_t)(base + c0 + tc) * ID + sloc8;
        }
        asm volatile("s_waitcnt vmcnt(0)" ::: "memory"); SB;

        int2 scA0, scA1, scB0, scB1;
        f32x16 acc[2][2] = {};

        MLP_KLOOP;

        #pragma unroll
        for (int nn = 0; nn < 2; nn++) {
            float bl = nn ? blB : blA;
            int row = nn ? rowB : rowA;
            #pragma unroll
            for (int mt = 0; mt < 2; mt++) {
                if (act[mt]) {
                    #pragma unroll
                    for (int r = 0; r < 16; r++) {
                        int m = (r & 3) + 8 * (r >> 2) + 4 * kh;
                        int tokg = c0 + (wt * 2 + mt) * 32 + m;
                        if (tokg < cnt) {
                            float y = acc[nn][mt][r] + bl;
                            yb[(size_t)(base + tokg) * HD + row] = (ushort)f2bf(y);
                        }
                    }
                }
            }
        }
    }
}

__global__ __launch_bounds__(256) void k_combine(
    const float* __restrict__ x, const ushort* __restrict__ yb,
    const int* __restrict__ top_idx, const float* __restrict__ top_wt,
    const int* __restrict__ pos_of, const int* __restrict__ offsets,
    float* __restrict__ out)
{
    int n = blockIdx.x, tid = threadIdx.x;
    float4 xv = ((const float4*)(x + (size_t)n * HD))[tid];
    float r0 = xv.x, r1 = xv.y, r2 = xv.z, r3 = xv.w;
    #pragma unroll
    for (int k = 0; k < 4; k++) {
        int e = top_idx[n * 4 + k];
        float wt = top_wt[n * 4 + k];
        int slot = offsets[e] + pos_of[n * 4 + k];
        ushort4 yv = ((const ushort4*)(yb + (size_t)slot * HD))[tid];
        r0 += wt * bf2f(yv.x); r1 += wt * bf2f(yv.y);
        r2 += wt * bf2f(yv.z); r3 += wt * bf2f(yv.w);
    }
    float4 ov; ov.x = r0; ov.y = r1; ov.z = r2; ov.w = r3;
    ((float4*)(out + (size_t)n * HD))[tid] = ov;
}

extern "C" void kernel_launch(void* const* d_in, const int* in_sizes, int n_in,
                              void* d_out, int out_size, void* d_ws, size_t ws_size,
                              hipStream_t stream)
{
    const float* x           = (const float*)d_in[0];
    const float* norm_w      = (const float*)d_in[1];
    const float* gate_w      = (const float*)d_in[2];
    const float* gate_b      = (const float*)d_in[3];
    const float* mlp1_bias   = (const float*)d_in[4];
    const float* mlp2_bias   = (const float*)d_in[5];
    const int*   mlp1_blocks = (const int*)d_in[6];
    const int*   mlp1_scales = (const int*)d_in[7];
    const int*   mlp2_blocks = (const int*)d_in[8];
    const int*   mlp2_scales = (const int*)d_in[9];
    float* out = (float*)d_out;

    char* ws = (char*)d_ws;
    ushort* t_bf16  = (ushort*)(ws + TB_OFF);
    ushort* a       = (ushort*)(ws + A_OFF);
    ushort* yb      = (ushort*)(ws + YB_OFF);
    int*   counts   = (int*)(ws + CNT_OFF);
    int*   offsets  = (int*)(ws + OFFS_OFF);
    int*   tok_list = (int*)(ws + TOKL_OFF);
    int*   top_idx  = (int*)(ws + TIDX_OFF);
    float* top_wt   = (float*)(ws + TWT_OFF);
    int*   pos_of   = (int*)(ws + POS_OFF);

    hipMemsetAsync(counts, 0, NE * sizeof(int), stream);
    k_gate<<<NTOK, 256, 0, stream>>>(x, norm_w, gate_w, gate_b, t_bf16, top_idx, top_wt,
                                     counts, tok_list, pos_of);
    k_prefix<<<1, 64, 0, stream>>>(counts, offsets);
    k_mlp1<<<dim3(16, NE), 256, 0, stream>>>(t_bf16, mlp1_blocks, mlp1_scales, mlp1_bias,
                                             counts, offsets, tok_list, a);
    k_mlp2<<<dim3(8, NE), 256, 0, stream>>>(a, mlp2_blocks, mlp2_scales, mlp2_bias,
                                            counts, offsets, yb);
    k_combine<<<NTOK, 256, 0, stream>>>(x, yb, top_idx, top_wt, pos_of, offsets, out);
}